// Round 2
// baseline (249.131 us; speedup 1.0000x reference)
//
#include <hip/hip_runtime.h>

// CommLayer: y[b,a,e] = tanh( xb[b,a,:]·M[e,:] + S[b,:]·Cn[e,:] ),
//   M = H - C/7, Cn = C/7, S[b] = sum_a xb[b,a,:].
// One K=128 fp16 MFMA GEMM, A_aug[m=(b,a)] = [xb | S(b)], B_aug[e] = [M[e] | Cn[e]].
// R2: barrier-free / LDS-free. A-fragments load straight from global (x is
// [B*8,64] row-major = exactly the MFMA A k-order); S comes from a 3-round
// fp32 __shfl_xor butterfly over the 8 agent-lanes (which also broadcasts it
// to the lanes that need it); B fragments persist in VGPRs per wave.
// Memory floor: 128 MB read + 128 MB write -> ~41 us at 6.3 TB/s.

typedef _Float16 half8v  __attribute__((ext_vector_type(8)));
typedef float    floatx4 __attribute__((ext_vector_type(4)));

#define WAVES_PER_BLOCK 4

__global__ __launch_bounds__(256, 4)
void comm_kernel(const float* __restrict__ x,
                 const float* __restrict__ Hw,
                 const float* __restrict__ Cw,
                 float* __restrict__ out,
                 int ntiles, int nwaves)
{
    const int tid  = threadIdx.x;
    const int lane = tid & 63;
    const int wave = tid >> 6;
    const int quad = lane >> 4;   // 0..3
    const int l16  = lane & 15;
    const int wgid = blockIdx.x * WAVES_PER_BLOCK + wave;

    // ---- Persistent B fragments (built once per wave, global -> VGPR) ----
    // B layout (16x16x32_f16): n = lane&15, k = quad*8 + j.
    // bfrag[kt][nt][j] = B_aug[e = nt*16 + l16][k = kt*32 + quad*8 + j]
    half8v bfrag[4][4];
    #pragma unroll
    for (int nt = 0; nt < 4; ++nt) {
        const float* hr = Hw + (nt * 16 + l16) * 64 + quad * 8;
        const float* cr = Cw + (nt * 16 + l16) * 64 + quad * 8;
        float h[16], c[16];
        *reinterpret_cast<float4*>(&h[0])  = *reinterpret_cast<const float4*>(hr);
        *reinterpret_cast<float4*>(&h[4])  = *reinterpret_cast<const float4*>(hr + 4);
        *reinterpret_cast<float4*>(&h[8])  = *reinterpret_cast<const float4*>(hr + 32);
        *reinterpret_cast<float4*>(&h[12]) = *reinterpret_cast<const float4*>(hr + 36);
        *reinterpret_cast<float4*>(&c[0])  = *reinterpret_cast<const float4*>(cr);
        *reinterpret_cast<float4*>(&c[4])  = *reinterpret_cast<const float4*>(cr + 4);
        *reinterpret_cast<float4*>(&c[8])  = *reinterpret_cast<const float4*>(cr + 32);
        *reinterpret_cast<float4*>(&c[12]) = *reinterpret_cast<const float4*>(cr + 36);
        half8v b0, b1, b2, b3;
        #pragma unroll
        for (int j = 0; j < 8; ++j) {
            b0[j] = (_Float16)(h[j]     - c[j]     * (1.0f / 7.0f));  // M, k=quad*8+j
            b1[j] = (_Float16)(h[8 + j] - c[8 + j] * (1.0f / 7.0f));  // M, k=32+...
            b2[j] = (_Float16)(c[j]     * (1.0f / 7.0f));             // Cn, k=64+...
            b3[j] = (_Float16)(c[8 + j] * (1.0f / 7.0f));             // Cn, k=96+...
        }
        bfrag[0][nt] = b0; bfrag[1][nt] = b1;
        bfrag[2][nt] = b2; bfrag[3][nt] = b3;
    }

    // ---- Main loop: one 16x64 m-tile per iteration, fully independent ----
    for (int t = wgid; t < ntiles; t += nwaves) {
        // A layout: m = l16 (agent-row within tile), k = quad*8 + j.
        // x row (row0+l16) has 64 floats; kt=0 -> cols quad*8, kt=1 -> cols 32+quad*8.
        const float* xt = x + (size_t)t * 1024 + l16 * 64 + quad * 8;
        float xf[16];
        *reinterpret_cast<float4*>(&xf[0])  = *reinterpret_cast<const float4*>(xt);
        *reinterpret_cast<float4*>(&xf[4])  = *reinterpret_cast<const float4*>(xt + 4);
        *reinterpret_cast<float4*>(&xf[8])  = *reinterpret_cast<const float4*>(xt + 32);
        *reinterpret_cast<float4*>(&xf[12]) = *reinterpret_cast<const float4*>(xt + 36);

        half8v af0, af1;
        #pragma unroll
        for (int j = 0; j < 8; ++j) {
            af0[j] = (_Float16)xf[j];
            af1[j] = (_Float16)xf[8 + j];
        }

        // S[b] = sum over 8 agent rows = butterfly over l16 bits 0..2 (fp32).
        // After this every lane holds S[batch(l16)] at its own k columns,
        // which is exactly the kt=2,3 augmented-A fragment.
        #pragma unroll
        for (int m = 1; m <= 4; m <<= 1) {
            #pragma unroll
            for (int j = 0; j < 16; ++j)
                xf[j] += __shfl_xor(xf[j], m, 64);
        }
        half8v af2, af3;
        #pragma unroll
        for (int j = 0; j < 8; ++j) {
            af2[j] = (_Float16)xf[j];
            af3[j] = (_Float16)xf[8 + j];
        }

        floatx4 acc[4];
        #pragma unroll
        for (int nt = 0; nt < 4; ++nt) acc[nt] = floatx4{0.f, 0.f, 0.f, 0.f};

        #pragma unroll
        for (int nt = 0; nt < 4; ++nt) {
            acc[nt] = __builtin_amdgcn_mfma_f32_16x16x32_f16(af0, bfrag[0][nt], acc[nt], 0, 0, 0);
            acc[nt] = __builtin_amdgcn_mfma_f32_16x16x32_f16(af1, bfrag[1][nt], acc[nt], 0, 0, 0);
            acc[nt] = __builtin_amdgcn_mfma_f32_16x16x32_f16(af2, bfrag[2][nt], acc[nt], 0, 0, 0);
            acc[nt] = __builtin_amdgcn_mfma_f32_16x16x32_f16(af3, bfrag[3][nt], acc[nt], 0, 0, 0);
        }

        // Epilogue: C/D layout col = l16, row = quad*4 + reg. tanh + store.
        float* o = out + (size_t)t * 1024;
        #pragma unroll
        for (int nt = 0; nt < 4; ++nt) {
            const int e = nt * 16 + l16;
            #pragma unroll
            for (int reg = 0; reg < 4; ++reg) {
                float y = acc[nt][reg];
                y = fminf(10.f, fmaxf(-10.f, y));
                const float tv  = __builtin_amdgcn_exp2f(y * 2.8853900817779268f); // e^{2y}
                const float res = (tv - 1.f) * __builtin_amdgcn_rcpf(tv + 1.f);
                o[(quad * 4 + reg) * 64 + e] = res;
            }
        }
    }
}

extern "C" void kernel_launch(void* const* d_in, const int* in_sizes, int n_in,
                              void* d_out, int out_size, void* d_ws, size_t ws_size,
                              hipStream_t stream) {
    const float* x  = (const float*)d_in[0];
    const float* Hw = (const float*)d_in[1];
    const float* Cw = (const float*)d_in[2];
    float* out = (float*)d_out;

    const int rows   = in_sizes[0] / 512;   // 65536 batch rows
    const int ntiles = rows * 8 / 16;       // 32768 m-tiles of 16 agent-rows
    const int blocks = 1024;                // 4096 waves -> 8 tiles/wave
    const int nwaves = blocks * WAVES_PER_BLOCK;
    comm_kernel<<<blocks, 256, 0, stream>>>(x, Hw, Cw, out, ntiles, nwaves);
}